// Round 4
// baseline (396.602 us; speedup 1.0000x reference)
//
#include <hip/hip_runtime.h>

typedef _Float16 f16;
typedef _Float16 f16x8 __attribute__((ext_vector_type(8)));
typedef float f32x4 __attribute__((ext_vector_type(4)));

// ---- workspace layout (bytes) ----
#define WS_ZCNN 0                      // 8192*128 f32 = 4 MiB
#define WS_EWIH 4194304                // enc Wih f16 [384][32] (k>=29 zero)
#define WS_EWHH 4218880                // enc Whh f16 [384][128]
#define WS_DWC  4317184                // dec combined f16 [512][128]
#define WS_DWHH 4448256                // dec Whh f16 [384][128]
#define WS_BIAS 4546560                // f32[1024]
#define WS_W1F  4550656                // conv1 B-frags f16 [9][16][32]
#define WS_W2F  4559872                // conv2 B-frags f16 [2][32][32]
#define WS_FCWF 4563968                // fc weights f16 [128][128]

static __device__ __forceinline__ f32x4 mfma16(f16x8 a, f16x8 b, f32x4 c) {
    return __builtin_amdgcn_mfma_f32_16x16x32_f16(a, b, c, 0, 0, 0);
}
static __device__ __forceinline__ float fexp2n(float x) {   // 2^(-x*log2e)
    return __builtin_amdgcn_exp2f(x * -1.4426950408889634f);
}

// ---------------- prep: f32 -> f16 packs ----------------
__global__ void k_prep(const float* __restrict__ eWih, const float* __restrict__ eWhh,
                       const float* __restrict__ ebih, const float* __restrict__ ebhh,
                       const float* __restrict__ dWih, const float* __restrict__ dWhh,
                       const float* __restrict__ dbih, const float* __restrict__ dbhh,
                       const float* __restrict__ w1, const float* __restrict__ w2,
                       const float* __restrict__ fcw,
                       char* __restrict__ ws)
{
    f16* ewih = (f16*)(ws + WS_EWIH);
    f16* ewhh = (f16*)(ws + WS_EWHH);
    f16* dwc  = (f16*)(ws + WS_DWC);
    f16* dwhh = (f16*)(ws + WS_DWHH);
    float* bias = (float*)(ws + WS_BIAS);
    f16* w1f = (f16*)(ws + WS_W1F);
    f16* w2f = (f16*)(ws + WS_W2F);
    f16* fcwf = (f16*)(ws + WS_FCWF);
    const int total = 12288 + 49152 + 65536 + 49152 + 1024 + 4608 + 2048 + 16384;
    for (int i = blockIdx.x * 256 + threadIdx.x; i < total; i += gridDim.x * 256) {
        int j = i;
        if (j < 12288) { int g = j >> 5, k = j & 31;
            ewih[j] = (f16)((k < 29) ? eWih[g * 29 + k] : 0.0f); continue; }
        j -= 12288;
        if (j < 49152) { ewhh[j] = (f16)eWhh[j]; continue; }
        j -= 49152;
        if (j < 65536) { int row = j >> 7, k = j & 127; float v;
            if (row < 256)      v = dWih[row * 128 + k] + dWhh[row * 128 + k];
            else if (row < 384) v = dWih[row * 128 + k];
            else                v = dWhh[(row - 128) * 128 + k];
            dwc[j] = (f16)v; continue; }
        j -= 65536;
        if (j < 49152) { dwhh[j] = (f16)dWhh[j]; continue; }
        j -= 49152;
        if (j < 1024) {
            if (j < 256)        bias[j] = ebih[j] + ebhh[j];
            else if (j < 384)   bias[j] = ebih[j];
            else if (j < 512)   bias[j] = ebhh[j - 128];
            else if (j < 768)   bias[j] = dbih[j - 512] + dbhh[j - 512];
            else if (j < 896)   bias[j] = dbih[j - 512];
            else                bias[j] = dbhh[j - 640];
            continue; }
        j -= 1024;
        if (j < 4608) {   // w1f[kk][co][k]: w1 (16,27,3,3) OIHW
            int kk = j >> 9, rem = j & 511, co = rem >> 5, k = rem & 31;
            w1f[j] = (f16)((k < 27) ? w1[co * 243 + k * 9 + kk] : 0.0f); continue; }
        j -= 4608;
        if (j < 2048) {   // w2f[s][co][k]: k<16 -> kk2=2s,ci=k ; k>=16 -> kk2=2s+1,ci=k-16
            int s = j >> 10, rem = j & 1023, co = rem >> 5, k = rem & 31;
            int kk2 = 2 * s + (k >= 16), ci = k & 15;
            w2f[j] = (f16)w2[co * 64 + ci * 4 + kk2]; continue; }
        j -= 2048;
        fcwf[j] = (f16)fcw[j];
    }
}

// ---------------- CNN: 16 images/block, MFMA f16 ----------------
#define IMG_STRIDE 2088   // f16; 1044 dw % 32 = 20 -> <=2-way LDS conflicts on A-frag reads
__global__ __launch_bounds__(256) void k_cnn(
    const float* __restrict__ cin,
    const float* __restrict__ b1, const float* __restrict__ b2,
    const float* __restrict__ fcb,
    char* __restrict__ ws)
{
    __shared__ __align__(16) f16 in_f[16 * IMG_STRIDE];   // [img][pix*32+ch]
    __shared__ __align__(16) f16 a1f[16][9][24];          // conv1 out (relu)
    __shared__ __align__(16) f16 vf[16][136];             // flat CHW conv2 out

    const int tid = threadIdx.x;
    const int base = blockIdx.x * 16;
    const f16* w1f = (const f16*)(ws + WS_W1F);
    const f16* w2f = (const f16*)(ws + WS_W2F);
    const f16* fcwf = (const f16*)(ws + WS_FCWF);
    float* z = (float*)(ws + WS_ZCNN);

    for (int i = tid; i < 16 * 1728; i += 256) {
        int img = i / 1728, rem = i % 1728;
        int pix = rem / 27, ci = rem % 27;
        in_f[img * IMG_STRIDE + pix * 32 + ci] = (f16)cin[(size_t)base * 1728 + i];
    }
    for (int i = tid; i < 16 * 64 * 5; i += 256) {
        int img = i / 320, r2 = i % 320;
        in_f[img * IMG_STRIDE + (r2 / 5) * 32 + 27 + r2 % 5] = (f16)0.0f;
    }
    __syncthreads();

    const int wv = tid >> 6, lane = tid & 63, nl = lane & 15, quad = lane >> 4;

    // conv1: 9 MFMAs per output position; A rows = contiguous channel vectors
    f16x8 bw1[9];
    #pragma unroll
    for (int kk = 0; kk < 9; kk++)
        bw1[kk] = *(const f16x8*)(w1f + (kk * 16 + nl) * 32 + quad * 8);
    float b1v = b1[nl];
    for (int p = wv; p < 9; p += 4) {
        int oy = p / 3, ox = p % 3;
        f32x4 acc = {b1v, b1v, b1v, b1v};
        #pragma unroll
        for (int kk = 0; kk < 9; kk++) {
            int pix = (2 * oy + kk / 3) * 8 + (2 * ox + kk % 3);
            f16x8 a = *(const f16x8*)(&in_f[nl * IMG_STRIDE + pix * 32 + quad * 8]);
            acc = mfma16(a, bw1[kk], acc);
        }
        #pragma unroll
        for (int r = 0; r < 4; r++)
            a1f[quad * 4 + r][p][nl] = (f16)fmaxf(acc[r], 0.0f);
    }
    __syncthreads();

    // conv2: wave = output pos (y,x); K=64 as 2 MFMA k-steps
    {
        int y = wv >> 1, x = wv & 1;
        #pragma unroll
        for (int nt = 0; nt < 2; nt++) {
            float bv = b2[nt * 16 + nl];
            f32x4 acc = {bv, bv, bv, bv};
            #pragma unroll
            for (int s = 0; s < 2; s++) {
                int kk2 = 2 * s + (quad >> 1);
                int pos1 = (y + (kk2 >> 1)) * 3 + (x + (kk2 & 1));
                f16x8 a = *(const f16x8*)(&a1f[nl][pos1][(quad & 1) * 8]);
                f16x8 b = *(const f16x8*)(w2f + ((size_t)s * 32 + nt * 16 + nl) * 32 + quad * 8);
                acc = mfma16(a, b, acc);
            }
            #pragma unroll
            for (int r = 0; r < 4; r++)
                vf[quad * 4 + r][(nt * 16 + nl) * 4 + (y * 2 + x)] = (f16)fmaxf(acc[r], 0.0f);
        }
    }
    __syncthreads();

    // fc 128->128: wave wv -> outputs wv*32..wv*32+31
    #pragma unroll
    for (int nt = 0; nt < 2; nt++) {
        int o = wv * 32 + nt * 16 + nl;
        float bv = fcb[o];
        f32x4 acc = {bv, bv, bv, bv};
        #pragma unroll
        for (int kt = 0; kt < 4; kt++) {
            f16x8 a = *(const f16x8*)(&vf[nl][kt * 32 + quad * 8]);
            f16x8 b = *(const f16x8*)(fcwf + o * 128 + kt * 32 + quad * 8);
            acc = mfma16(a, b, acc);
        }
        #pragma unroll
        for (int r = 0; r < 4; r++)
            z[(size_t)(base + quad * 4 + r) * 128 + o] = fmaxf(acc[r], 0.0f);
    }
}

// ---------------- GRU: 512 threads, 16 rows/block, wave owns 16 cols ----------------
// __launch_bounds__(512,2): allow up to 256 VGPR so weight frags stay register-resident
// (round-3 (512,4) -> VGPR=64 -> compiler rematerialized 16 global loads/step).
__global__ __launch_bounds__(512, 2) void k_gru(
    const float* __restrict__ lin,
    const char* __restrict__ ws,
    const float* __restrict__ dis_w, const float* __restrict__ dis_b,
    const float* __restrict__ value_w, const float* __restrict__ value_b,
    float* __restrict__ out)
{
    const int tid = threadIdx.x;
    const int wv = tid >> 6;
    const int lane = tid & 63;
    const int nl = lane & 15;
    const int quad = lane >> 4;
    const int j0 = wv * 16;
    const int row0 = blockIdx.x * 16;

    const f16* ewih = (const f16*)(ws + WS_EWIH);
    const f16* ewhh = (const f16*)(ws + WS_EWHH);
    const f16* dwc  = (const f16*)(ws + WS_DWC);
    const f16* dwhh = (const f16*)(ws + WS_DWHH);
    const float* bias = (const float*)(ws + WS_BIAS);
    const float* z_cnn = (const float*)(ws + WS_ZCNN);

    // h_s: swizzled (rows 8-15 rotated +16 cols) -> conflict-free b16 writes, clean b128 reads
    __shared__ __align__(16) f16 h_s[2][16][136];
    __shared__ __align__(16) f16 x_s[2][16][32];
    __shared__ __align__(16) float pn_s[16][264];

    for (int i = tid; i < 2 * 16 * 136; i += 512) ((f16*)h_s)[i] = (f16)0.0f;

    const int rsw = (nl & 8) ? 16 : 0;    // read-side swizzle (row = nl)
    const int wrow = quad * 4;            // write rows wrow..wrow+3
    const int wsw = (quad >= 2) ? 16 : 0; // write-side swizzle (rows 8-15)
    const int wcol = (j0 + nl + wsw) & 127;
    const int c0 = (quad * 8 + rsw) & 127;
    const int c1 = (32 + quad * 8 + rsw) & 127;
    const int c2 = (64 + quad * 8 + rsw) & 127;
    const int c3 = (96 + quad * 8 + rsw) & 127;

    float ho[4];
    #pragma unroll
    for (int r = 0; r < 4; r++) ho[r] = 0.0f;

    const int xr = tid >> 5, xc = tid & 31;   // x staging: 16 rows x 32 cols
    const bool xok = (xc < 29);
    const size_t lin_base = (size_t)(row0 + xr) * 1856 + xc;

    // ================= encoder =================
    {
        float eb_r, eb_z, eb_xn, eb_hn;
        { int c = j0 + nl;
          eb_r = bias[c]; eb_z = bias[128 + c]; eb_xn = bias[256 + c]; eb_hn = bias[384 + c]; }
        f16x8 we_r[4], we_z[4], we_hn[4], we_xr, we_xz, we_xn;
        { int gr = j0 + nl;
          #pragma unroll
          for (int kt = 0; kt < 4; kt++) {
              we_r[kt]  = *(const f16x8*)(ewhh + gr * 128 + kt * 32 + quad * 8);
              we_z[kt]  = *(const f16x8*)(ewhh + (128 + gr) * 128 + kt * 32 + quad * 8);
              we_hn[kt] = *(const f16x8*)(ewhh + (256 + gr) * 128 + kt * 32 + quad * 8);
          }
          we_xr = *(const f16x8*)(ewih + gr * 32 + quad * 8);
          we_xz = *(const f16x8*)(ewih + (128 + gr) * 32 + quad * 8);
          we_xn = *(const f16x8*)(ewih + (256 + gr) * 32 + quad * 8);
        }

        float xv = xok ? lin[lin_base] : 0.0f;

#define ENC_STEP(BUF, OBUF, TN)                                                      \
        do {                                                                         \
            x_s[BUF][xr][xc] = (f16)xv;                                              \
            __syncthreads();                                                         \
            f16x8 ax = *(const f16x8*)(&x_s[BUF][nl][quad * 8]);                     \
            f16x8 ah0 = *(const f16x8*)(&h_s[BUF][nl][c0]);                          \
            f16x8 ah1 = *(const f16x8*)(&h_s[BUF][nl][c1]);                          \
            f16x8 ah2 = *(const f16x8*)(&h_s[BUF][nl][c2]);                          \
            f16x8 ah3 = *(const f16x8*)(&h_s[BUF][nl][c3]);                          \
            if ((TN) < 64) xv = xok ? lin[lin_base + (TN) * 29] : 0.0f;              \
            f32x4 aR  = {eb_r, eb_r, eb_r, eb_r};                                    \
            f32x4 aZ  = {eb_z, eb_z, eb_z, eb_z};                                    \
            f32x4 aXN = {eb_xn, eb_xn, eb_xn, eb_xn};                                \
            f32x4 aHN = {eb_hn, eb_hn, eb_hn, eb_hn};                                \
            aR  = mfma16(ax, we_xr, aR);                                             \
            aZ  = mfma16(ax, we_xz, aZ);                                             \
            aXN = mfma16(ax, we_xn, aXN);                                            \
            aR  = mfma16(ah0, we_r[0], aR);  aR  = mfma16(ah1, we_r[1], aR);         \
            aR  = mfma16(ah2, we_r[2], aR);  aR  = mfma16(ah3, we_r[3], aR);         \
            aZ  = mfma16(ah0, we_z[0], aZ);  aZ  = mfma16(ah1, we_z[1], aZ);         \
            aZ  = mfma16(ah2, we_z[2], aZ);  aZ  = mfma16(ah3, we_z[3], aZ);         \
            aHN = mfma16(ah0, we_hn[0], aHN); aHN = mfma16(ah1, we_hn[1], aHN);      \
            aHN = mfma16(ah2, we_hn[2], aHN); aHN = mfma16(ah3, we_hn[3], aHN);      \
            _Pragma("unroll")                                                        \
            for (int r = 0; r < 4; r++) {                                            \
                float ea = fexp2n(aR[r]), eb = fexp2n(aZ[r]);                        \
                float s1 = 1.0f + ea, s2 = 1.0f + eb;                                \
                float R = __builtin_amdgcn_rcpf(s1 * s2);                            \
                float rg = s2 * R, zg = s1 * R;                                      \
                float ec = fexp2n(2.0f * (aXN[r] + rg * aHN[r]));                    \
                float ng = (1.0f - ec) * __builtin_amdgcn_rcpf(1.0f + ec);           \
                float h = (1.0f - zg) * ng + zg * ho[r];                             \
                ho[r] = h;                                                           \
                h_s[OBUF][wrow + r][wcol] = (f16)h;                                  \
            }                                                                        \
        } while (0)

        for (int t = 0; t < 64; t += 2) {
            ENC_STEP(0, 1, t + 1);
            ENC_STEP(1, 0, t + 2);
        }
#undef ENC_STEP
    }

    // ================= decoder =================
    float db_r, db_z, db_xn, db_hn;
    { int c = j0 + nl;
      db_r = bias[512 + c]; db_z = bias[640 + c]; db_xn = bias[768 + c]; db_hn = bias[896 + c]; }

    // step 0: xin = 0 -> gx = bih; Whh-only frags streamed once (reads h_s[0], writes h_s[1])
    {
        __syncthreads();
        f16x8 ah0 = *(const f16x8*)(&h_s[0][nl][c0]);
        f16x8 ah1 = *(const f16x8*)(&h_s[0][nl][c1]);
        f16x8 ah2 = *(const f16x8*)(&h_s[0][nl][c2]);
        f16x8 ah3 = *(const f16x8*)(&h_s[0][nl][c3]);
        int gr = j0 + nl;
        f32x4 aR  = {db_r, db_r, db_r, db_r};
        f32x4 aZ  = {db_z, db_z, db_z, db_z};
        f32x4 aHN = {db_hn, db_hn, db_hn, db_hn};
        #pragma unroll
        for (int kt = 0; kt < 4; kt++) {
            f16x8 b0 = *(const f16x8*)(dwhh + gr * 128 + kt * 32 + quad * 8);
            f16x8 b1 = *(const f16x8*)(dwhh + (128 + gr) * 128 + kt * 32 + quad * 8);
            f16x8 b2 = *(const f16x8*)(dwhh + (256 + gr) * 128 + kt * 32 + quad * 8);
            f16x8 a = (kt == 0) ? ah0 : (kt == 1) ? ah1 : (kt == 2) ? ah2 : ah3;
            aR  = mfma16(a, b0, aR);
            aZ  = mfma16(a, b1, aZ);
            aHN = mfma16(a, b2, aHN);
        }
        #pragma unroll
        for (int r = 0; r < 4; r++) {
            float ea = fexp2n(aR[r]), eb = fexp2n(aZ[r]);
            float s1 = 1.0f + ea, s2 = 1.0f + eb;
            float R = __builtin_amdgcn_rcpf(s1 * s2);
            float rg = s2 * R, zg = s1 * R;
            float ec = fexp2n(2.0f * (db_xn + rg * aHN[r]));
            float ng = (1.0f - ec) * __builtin_amdgcn_rcpf(1.0f + ec);
            float h = (1.0f - zg) * ng + zg * ho[r];
            ho[r] = h;
            h_s[1][wrow + r][wcol] = (f16)h;
        }
    }
    // steps 1..63: xin == h -> combined weights, register-resident
    {
        f16x8 wd_r[4], wd_z[4], wd_xn[4], wd_hn[4];
        { int gr = j0 + nl;
          #pragma unroll
          for (int kt = 0; kt < 4; kt++) {
              wd_r[kt]  = *(const f16x8*)(dwc + gr * 128 + kt * 32 + quad * 8);
              wd_z[kt]  = *(const f16x8*)(dwc + (128 + gr) * 128 + kt * 32 + quad * 8);
              wd_xn[kt] = *(const f16x8*)(dwc + (256 + gr) * 128 + kt * 32 + quad * 8);
              wd_hn[kt] = *(const f16x8*)(dwc + (384 + gr) * 128 + kt * 32 + quad * 8);
          }
        }

#define DEC_STEP(BUF, OBUF)                                                          \
        do {                                                                         \
            __syncthreads();                                                         \
            f16x8 ah0 = *(const f16x8*)(&h_s[BUF][nl][c0]);                          \
            f16x8 ah1 = *(const f16x8*)(&h_s[BUF][nl][c1]);                          \
            f16x8 ah2 = *(const f16x8*)(&h_s[BUF][nl][c2]);                          \
            f16x8 ah3 = *(const f16x8*)(&h_s[BUF][nl][c3]);                          \
            f32x4 aR  = {db_r, db_r, db_r, db_r};                                    \
            f32x4 aZ  = {db_z, db_z, db_z, db_z};                                    \
            f32x4 aXN = {db_xn, db_xn, db_xn, db_xn};                                \
            f32x4 aHN = {db_hn, db_hn, db_hn, db_hn};                                \
            aR  = mfma16(ah0, wd_r[0], aR);   aR  = mfma16(ah1, wd_r[1], aR);        \
            aR  = mfma16(ah2, wd_r[2], aR);   aR  = mfma16(ah3, wd_r[3], aR);        \
            aZ  = mfma16(ah0, wd_z[0], aZ);   aZ  = mfma16(ah1, wd_z[1], aZ);        \
            aZ  = mfma16(ah2, wd_z[2], aZ);   aZ  = mfma16(ah3, wd_z[3], aZ);        \
            aXN = mfma16(ah0, wd_xn[0], aXN); aXN = mfma16(ah1, wd_xn[1], aXN);      \
            aXN = mfma16(ah2, wd_xn[2], aXN); aXN = mfma16(ah3, wd_xn[3], aXN);      \
            aHN = mfma16(ah0, wd_hn[0], aHN); aHN = mfma16(ah1, wd_hn[1], aHN);      \
            aHN = mfma16(ah2, wd_hn[2], aHN); aHN = mfma16(ah3, wd_hn[3], aHN);      \
            _Pragma("unroll")                                                        \
            for (int r = 0; r < 4; r++) {                                            \
                float ea = fexp2n(aR[r]), eb = fexp2n(aZ[r]);                        \
                float s1 = 1.0f + ea, s2 = 1.0f + eb;                                \
                float R = __builtin_amdgcn_rcpf(s1 * s2);                            \
                float rg = s2 * R, zg = s1 * R;                                      \
                float ec = fexp2n(2.0f * (aXN[r] + rg * aHN[r]));                    \
                float ng = (1.0f - ec) * __builtin_amdgcn_rcpf(1.0f + ec);           \
                float h = (1.0f - zg) * ng + zg * ho[r];                             \
                ho[r] = h;                                                           \
                h_s[OBUF][wrow + r][wcol] = (f16)h;                                  \
            }                                                                        \
        } while (0)

        DEC_STEP(1, 0);            // step 1
        for (int t = 2; t < 64; t += 2) {
            DEC_STEP(0, 1);
            DEC_STEP(1, 0);
        }
#undef DEC_STEP
    }

    // ================= heads =================
    #pragma unroll
    for (int r = 0; r < 4; r++)
        pn_s[wrow + r][128 + j0 + nl] = ho[r];
    for (int i = tid; i < 16 * 128; i += 512) {
        int rr = i >> 7, cc = i & 127;
        pn_s[rr][cc] = z_cnn[(size_t)(row0 + rr) * 128 + cc];
    }
    __syncthreads();

    const int rr = tid & 15, og = tid >> 4;   // og 0..31
    const float4* pr4 = (const float4*)(&pn_s[rr][0]);
    for (int o = og; o < 79; o += 32) {
        const float* wrow_p = (o < 78) ? (dis_w + o * 256) : value_w;
        float acc = (o < 78) ? dis_b[o] : value_b[0];
        const float4* wr4 = (const float4*)wrow_p;
        #pragma unroll 8
        for (int k = 0; k < 64; k++) {
            float4 a = wr4[k], b = pr4[k];
            acc += a.x * b.x + a.y * b.y + a.z * b.z + a.w * b.w;
        }
        if (o < 78) out[(size_t)(row0 + rr) * 78 + o] = acc;
        else        out[(size_t)8192 * 78 + row0 + rr] = acc;
    }
}

extern "C" void kernel_launch(void* const* d_in, const int* in_sizes, int n_in,
                              void* d_out, int out_size, void* d_ws, size_t ws_size,
                              hipStream_t stream)
{
    (void)in_sizes; (void)n_in; (void)out_size; (void)ws_size;
    const float* cnn  = (const float*)d_in[0];
    const float* lin  = (const float*)d_in[1];
    const float* c1w  = (const float*)d_in[2];
    const float* c1b  = (const float*)d_in[3];
    const float* c2w  = (const float*)d_in[4];
    const float* c2b  = (const float*)d_in[5];
    const float* fcw  = (const float*)d_in[6];
    const float* fcb  = (const float*)d_in[7];
    const float* eWih = (const float*)d_in[8];
    const float* eWhh = (const float*)d_in[9];
    const float* ebih = (const float*)d_in[10];
    const float* ebhh = (const float*)d_in[11];
    const float* dWih = (const float*)d_in[12];
    const float* dWhh = (const float*)d_in[13];
    const float* dbih = (const float*)d_in[14];
    const float* dbhh = (const float*)d_in[15];
    const float* disw = (const float*)d_in[16];
    const float* disb = (const float*)d_in[17];
    const float* vw   = (const float*)d_in[18];
    const float* vb   = (const float*)d_in[19];
    char* ws = (char*)d_ws;
    float* out = (float*)d_out;

    hipLaunchKernelGGL(k_prep, dim3(128), dim3(256), 0, stream,
                       eWih, eWhh, ebih, ebhh, dWih, dWhh, dbih, dbhh,
                       c1w, c2w, fcw, ws);
    hipLaunchKernelGGL(k_cnn, dim3(512), dim3(256), 0, stream,
                       cnn, c1b, c2b, fcb, ws);
    hipLaunchKernelGGL(k_gru, dim3(512), dim3(512), 0, stream,
                       lin, ws, disw, disb, vw, vb, out);
}

// Round 5
// 350.042 us; speedup vs baseline: 1.1330x; 1.1330x over previous
//
#include <hip/hip_runtime.h>

typedef _Float16 f16;
typedef _Float16 f16x8 __attribute__((ext_vector_type(8)));
typedef float f32x4 __attribute__((ext_vector_type(4)));

// ---- workspace layout (bytes) ----
#define WS_ZCNN 0                      // 8192*128 f32 = 4 MiB
#define WS_EWIH 4194304                // enc Wih f16 [384][32] (k>=29 zero)
#define WS_EWHH 4218880                // enc Whh f16 [384][128]
#define WS_DWC  4317184                // dec combined f16 [512][128]
#define WS_DWHH 4448256                // dec Whh f16 [384][128]
#define WS_BIAS 4546560                // f32[1024]
#define WS_W1F  4550656                // conv1 B-frags f16 [9][16][32]
#define WS_W2F  4559872                // conv2 B-frags f16 [2][32][32]
#define WS_FCWF 4563968                // fc weights f16 [128][128]

static __device__ __forceinline__ f32x4 mfma16(f16x8 a, f16x8 b, f32x4 c) {
    return __builtin_amdgcn_mfma_f32_16x16x32_f16(a, b, c, 0, 0, 0);
}
static __device__ __forceinline__ float fexp2n(float x) {   // 2^(-x*log2e)
    return __builtin_amdgcn_exp2f(x * -1.4426950408889634f);
}
// Pin a fragment in VGPRs: INLINEASM defs are not rematerializable, so the
// compiler cannot re-issue the global load each loop iteration.
static __device__ __forceinline__ void pin(f16x8& x) { asm volatile("" : "+v"(x)); }

// ---------------- prep: f32 -> f16 packs ----------------
__global__ void k_prep(const float* __restrict__ eWih, const float* __restrict__ eWhh,
                       const float* __restrict__ ebih, const float* __restrict__ ebhh,
                       const float* __restrict__ dWih, const float* __restrict__ dWhh,
                       const float* __restrict__ dbih, const float* __restrict__ dbhh,
                       const float* __restrict__ w1, const float* __restrict__ w2,
                       const float* __restrict__ fcw,
                       char* __restrict__ ws)
{
    f16* ewih = (f16*)(ws + WS_EWIH);
    f16* ewhh = (f16*)(ws + WS_EWHH);
    f16* dwc  = (f16*)(ws + WS_DWC);
    f16* dwhh = (f16*)(ws + WS_DWHH);
    float* bias = (float*)(ws + WS_BIAS);
    f16* w1f = (f16*)(ws + WS_W1F);
    f16* w2f = (f16*)(ws + WS_W2F);
    f16* fcwf = (f16*)(ws + WS_FCWF);
    const int total = 12288 + 49152 + 65536 + 49152 + 1024 + 4608 + 2048 + 16384;
    for (int i = blockIdx.x * 256 + threadIdx.x; i < total; i += gridDim.x * 256) {
        int j = i;
        if (j < 12288) { int g = j >> 5, k = j & 31;
            ewih[j] = (f16)((k < 29) ? eWih[g * 29 + k] : 0.0f); continue; }
        j -= 12288;
        if (j < 49152) { ewhh[j] = (f16)eWhh[j]; continue; }
        j -= 49152;
        if (j < 65536) { int row = j >> 7, k = j & 127; float v;
            if (row < 256)      v = dWih[row * 128 + k] + dWhh[row * 128 + k];
            else if (row < 384) v = dWih[row * 128 + k];
            else                v = dWhh[(row - 128) * 128 + k];
            dwc[j] = (f16)v; continue; }
        j -= 65536;
        if (j < 49152) { dwhh[j] = (f16)dWhh[j]; continue; }
        j -= 49152;
        if (j < 1024) {
            if (j < 256)        bias[j] = ebih[j] + ebhh[j];
            else if (j < 384)   bias[j] = ebih[j];
            else if (j < 512)   bias[j] = ebhh[j - 128];
            else if (j < 768)   bias[j] = dbih[j - 512] + dbhh[j - 512];
            else if (j < 896)   bias[j] = dbih[j - 512];
            else                bias[j] = dbhh[j - 640];
            continue; }
        j -= 1024;
        if (j < 4608) {   // w1f[kk][co][k]: w1 (16,27,3,3) OIHW; k>=27 -> 0
            int kk = j >> 9, rem = j & 511, co = rem >> 5, k = rem & 31;
            w1f[j] = (f16)((k < 27) ? w1[co * 243 + k * 9 + kk] : 0.0f); continue; }
        j -= 4608;
        if (j < 2048) {   // w2f[s][co][k]
            int s = j >> 10, rem = j & 1023, co = rem >> 5, k = rem & 31;
            int kk2 = 2 * s + (k >= 16), ci = k & 15;
            w2f[j] = (f16)w2[co * 64 + ci * 4 + kk2]; continue; }
        j -= 2048;
        fcwf[j] = (f16)fcw[j];
    }
}

// ---------------- CNN: 16 images/block, no input staging, ~11 KB LDS ----------------
// conv1 A-frag pad channels (27..31) multiply ZERO B rows (w1f zeroed in k_prep),
// so A can load 8 raw floats straight from global: no mask, no LDS staging.
// Max addr: pix<=54 -> 54*27+31 = 1489 < 1728, never OOB.
__global__ __launch_bounds__(256) void k_cnn(
    const float* __restrict__ cin,
    const float* __restrict__ b1, const float* __restrict__ b2,
    const float* __restrict__ fcb,
    char* __restrict__ ws)
{
    __shared__ __align__(16) f16 a1f[16][9][24];   // conv1 out (relu)
    __shared__ __align__(16) f16 vf[16][136];      // flat CHW conv2 out

    const int tid = threadIdx.x;
    const int base = blockIdx.x * 16;
    const f16* w1f = (const f16*)(ws + WS_W1F);
    const f16* w2f = (const f16*)(ws + WS_W2F);
    const f16* fcwf = (const f16*)(ws + WS_FCWF);
    float* z = (float*)(ws + WS_ZCNN);

    const int wv = tid >> 6, lane = tid & 63, nl = lane & 15, quad = lane >> 4;

    // conv1: 9 MFMAs per output position; A loaded direct from global + cvt
    f16x8 bw1[9];
    #pragma unroll
    for (int kk = 0; kk < 9; kk++)
        bw1[kk] = *(const f16x8*)(w1f + (kk * 16 + nl) * 32 + quad * 8);
    float b1v = b1[nl];
    const float* imgp = cin + (size_t)(base + nl) * 1728 + quad * 8;
    for (int p = wv; p < 9; p += 4) {
        int oy = p / 3, ox = p % 3;
        f32x4 acc = {b1v, b1v, b1v, b1v};
        #pragma unroll
        for (int kk = 0; kk < 9; kk++) {
            int pix = (2 * oy + kk / 3) * 8 + (2 * ox + kk % 3);
            const float* s = imgp + pix * 27;
            f16x8 a;
            #pragma unroll
            for (int jj = 0; jj < 8; jj++) a[jj] = (f16)s[jj];
            acc = mfma16(a, bw1[kk], acc);
        }
        #pragma unroll
        for (int r = 0; r < 4; r++)
            a1f[quad * 4 + r][p][nl] = (f16)fmaxf(acc[r], 0.0f);
    }
    __syncthreads();

    // conv2: wave = output pos (y,x); K=64 as 2 MFMA k-steps
    {
        int y = wv >> 1, x = wv & 1;
        #pragma unroll
        for (int nt = 0; nt < 2; nt++) {
            float bv = b2[nt * 16 + nl];
            f32x4 acc = {bv, bv, bv, bv};
            #pragma unroll
            for (int s = 0; s < 2; s++) {
                int kk2 = 2 * s + (quad >> 1);
                int pos1 = (y + (kk2 >> 1)) * 3 + (x + (kk2 & 1));
                f16x8 a = *(const f16x8*)(&a1f[nl][pos1][(quad & 1) * 8]);
                f16x8 b = *(const f16x8*)(w2f + ((size_t)s * 32 + nt * 16 + nl) * 32 + quad * 8);
                acc = mfma16(a, b, acc);
            }
            #pragma unroll
            for (int r = 0; r < 4; r++)
                vf[quad * 4 + r][(nt * 16 + nl) * 4 + (y * 2 + x)] = (f16)fmaxf(acc[r], 0.0f);
        }
    }
    __syncthreads();

    // fc 128->128: wave wv -> outputs wv*32..wv*32+31
    #pragma unroll
    for (int nt = 0; nt < 2; nt++) {
        int o = wv * 32 + nt * 16 + nl;
        float bv = fcb[o];
        f32x4 acc = {bv, bv, bv, bv};
        #pragma unroll
        for (int kt = 0; kt < 4; kt++) {
            f16x8 a = *(const f16x8*)(&vf[nl][kt * 32 + quad * 8]);
            f16x8 b = *(const f16x8*)(fcwf + o * 128 + kt * 32 + quad * 8);
            acc = mfma16(a, b, acc);
        }
        #pragma unroll
        for (int r = 0; r < 4; r++)
            z[(size_t)(base + quad * 4 + r) * 128 + o] = fmaxf(acc[r], 0.0f);
    }
}

// ---------------- GRU: 512 threads, 16 rows/block, wave owns 16 cols ----------------
// (512,4): 2 blocks/CU. Weight frags asm-pinned so the compiler cannot
// rematerialize the global loads inside the step loops (r3/r4 showed it does).
__global__ __launch_bounds__(512, 4) void k_gru(
    const float* __restrict__ lin,
    const char* __restrict__ ws,
    const float* __restrict__ dis_w, const float* __restrict__ dis_b,
    const float* __restrict__ value_w, const float* __restrict__ value_b,
    float* __restrict__ out)
{
    const int tid = threadIdx.x;
    const int wv = tid >> 6;
    const int lane = tid & 63;
    const int nl = lane & 15;
    const int quad = lane >> 4;
    const int j0 = wv * 16;
    const int row0 = blockIdx.x * 16;

    const f16* ewih = (const f16*)(ws + WS_EWIH);
    const f16* ewhh = (const f16*)(ws + WS_EWHH);
    const f16* dwc  = (const f16*)(ws + WS_DWC);
    const f16* dwhh = (const f16*)(ws + WS_DWHH);
    const float* bias = (const float*)(ws + WS_BIAS);
    const float* z_cnn = (const float*)(ws + WS_ZCNN);

    // h_s: swizzled (rows 8-15 rotated +16 cols) -> conflict-free b16 writes, clean b128 reads
    __shared__ __align__(16) f16 h_s[2][16][136];
    __shared__ __align__(16) f16 x_s[2][16][32];
    __shared__ __align__(16) float pn_s[16][264];

    for (int i = tid; i < 2 * 16 * 136; i += 512) ((f16*)h_s)[i] = (f16)0.0f;

    const int rsw = (nl & 8) ? 16 : 0;    // read-side swizzle (row = nl)
    const int wrow = quad * 4;            // write rows wrow..wrow+3
    const int wsw = (quad >= 2) ? 16 : 0; // write-side swizzle (rows 8-15)
    const int wcol = (j0 + nl + wsw) & 127;
    const int c0 = (quad * 8 + rsw) & 127;
    const int c1 = (32 + quad * 8 + rsw) & 127;
    const int c2 = (64 + quad * 8 + rsw) & 127;
    const int c3 = (96 + quad * 8 + rsw) & 127;

    float ho[4];
    #pragma unroll
    for (int r = 0; r < 4; r++) ho[r] = 0.0f;

    const int xr = tid >> 5, xc = tid & 31;   // x staging: 16 rows x 32 cols
    const bool xok = (xc < 29);
    const size_t lin_base = (size_t)(row0 + xr) * 1856 + xc;

    // ================= encoder =================
    {
        float eb_r, eb_z, eb_xn, eb_hn;
        { int c = j0 + nl;
          eb_r = bias[c]; eb_z = bias[128 + c]; eb_xn = bias[256 + c]; eb_hn = bias[384 + c]; }
        f16x8 we_r[4], we_z[4], we_hn[4], we_xr, we_xz, we_xn;
        { int gr = j0 + nl;
          #pragma unroll
          for (int kt = 0; kt < 4; kt++) {
              we_r[kt]  = *(const f16x8*)(ewhh + gr * 128 + kt * 32 + quad * 8);
              we_z[kt]  = *(const f16x8*)(ewhh + (128 + gr) * 128 + kt * 32 + quad * 8);
              we_hn[kt] = *(const f16x8*)(ewhh + (256 + gr) * 128 + kt * 32 + quad * 8);
              pin(we_r[kt]); pin(we_z[kt]); pin(we_hn[kt]);
          }
          we_xr = *(const f16x8*)(ewih + gr * 32 + quad * 8);
          we_xz = *(const f16x8*)(ewih + (128 + gr) * 32 + quad * 8);
          we_xn = *(const f16x8*)(ewih + (256 + gr) * 32 + quad * 8);
          pin(we_xr); pin(we_xz); pin(we_xn);
        }

        float xv = xok ? lin[lin_base] : 0.0f;

#define ENC_STEP(BUF, OBUF, TN)                                                      \
        do {                                                                         \
            x_s[BUF][xr][xc] = (f16)xv;                                              \
            __syncthreads();                                                         \
            f16x8 ax = *(const f16x8*)(&x_s[BUF][nl][quad * 8]);                     \
            f16x8 ah0 = *(const f16x8*)(&h_s[BUF][nl][c0]);                          \
            f16x8 ah1 = *(const f16x8*)(&h_s[BUF][nl][c1]);                          \
            f16x8 ah2 = *(const f16x8*)(&h_s[BUF][nl][c2]);                          \
            f16x8 ah3 = *(const f16x8*)(&h_s[BUF][nl][c3]);                          \
            if ((TN) < 64) xv = xok ? lin[lin_base + (TN) * 29] : 0.0f;              \
            f32x4 aR  = {eb_r, eb_r, eb_r, eb_r};                                    \
            f32x4 aZ  = {eb_z, eb_z, eb_z, eb_z};                                    \
            f32x4 aXN = {eb_xn, eb_xn, eb_xn, eb_xn};                                \
            f32x4 aHN = {eb_hn, eb_hn, eb_hn, eb_hn};                                \
            aR  = mfma16(ax, we_xr, aR);                                             \
            aZ  = mfma16(ax, we_xz, aZ);                                             \
            aXN = mfma16(ax, we_xn, aXN);                                            \
            aR  = mfma16(ah0, we_r[0], aR);  aR  = mfma16(ah1, we_r[1], aR);         \
            aR  = mfma16(ah2, we_r[2], aR);  aR  = mfma16(ah3, we_r[3], aR);         \
            aZ  = mfma16(ah0, we_z[0], aZ);  aZ  = mfma16(ah1, we_z[1], aZ);         \
            aZ  = mfma16(ah2, we_z[2], aZ);  aZ  = mfma16(ah3, we_z[3], aZ);         \
            aHN = mfma16(ah0, we_hn[0], aHN); aHN = mfma16(ah1, we_hn[1], aHN);      \
            aHN = mfma16(ah2, we_hn[2], aHN); aHN = mfma16(ah3, we_hn[3], aHN);      \
            _Pragma("unroll")                                                        \
            for (int r = 0; r < 4; r++) {                                            \
                float ea = fexp2n(aR[r]), eb = fexp2n(aZ[r]);                        \
                float s1 = 1.0f + ea, s2 = 1.0f + eb;                                \
                float R = __builtin_amdgcn_rcpf(s1 * s2);                            \
                float rg = s2 * R, zg = s1 * R;                                      \
                float ec = fexp2n(2.0f * (aXN[r] + rg * aHN[r]));                    \
                float ng = (1.0f - ec) * __builtin_amdgcn_rcpf(1.0f + ec);           \
                float h = (1.0f - zg) * ng + zg * ho[r];                             \
                ho[r] = h;                                                           \
                h_s[OBUF][wrow + r][wcol] = (f16)h;                                  \
            }                                                                        \
        } while (0)

        for (int t = 0; t < 64; t += 2) {
            ENC_STEP(0, 1, t + 1);
            ENC_STEP(1, 0, t + 2);
        }
#undef ENC_STEP
    }

    // ================= decoder =================
    float db_r, db_z, db_xn, db_hn;
    { int c = j0 + nl;
      db_r = bias[512 + c]; db_z = bias[640 + c]; db_xn = bias[768 + c]; db_hn = bias[896 + c]; }

    // step 0: xin = 0 -> gx = bih; Whh-only frags streamed once (reads h_s[0], writes h_s[1])
    {
        __syncthreads();
        f16x8 ah0 = *(const f16x8*)(&h_s[0][nl][c0]);
        f16x8 ah1 = *(const f16x8*)(&h_s[0][nl][c1]);
        f16x8 ah2 = *(const f16x8*)(&h_s[0][nl][c2]);
        f16x8 ah3 = *(const f16x8*)(&h_s[0][nl][c3]);
        int gr = j0 + nl;
        f32x4 aR  = {db_r, db_r, db_r, db_r};
        f32x4 aZ  = {db_z, db_z, db_z, db_z};
        f32x4 aHN = {db_hn, db_hn, db_hn, db_hn};
        #pragma unroll
        for (int kt = 0; kt < 4; kt++) {
            f16x8 b0 = *(const f16x8*)(dwhh + gr * 128 + kt * 32 + quad * 8);
            f16x8 b1 = *(const f16x8*)(dwhh + (128 + gr) * 128 + kt * 32 + quad * 8);
            f16x8 b2 = *(const f16x8*)(dwhh + (256 + gr) * 128 + kt * 32 + quad * 8);
            f16x8 a = (kt == 0) ? ah0 : (kt == 1) ? ah1 : (kt == 2) ? ah2 : ah3;
            aR  = mfma16(a, b0, aR);
            aZ  = mfma16(a, b1, aZ);
            aHN = mfma16(a, b2, aHN);
        }
        #pragma unroll
        for (int r = 0; r < 4; r++) {
            float ea = fexp2n(aR[r]), eb = fexp2n(aZ[r]);
            float s1 = 1.0f + ea, s2 = 1.0f + eb;
            float R = __builtin_amdgcn_rcpf(s1 * s2);
            float rg = s2 * R, zg = s1 * R;
            float ec = fexp2n(2.0f * (db_xn + rg * aHN[r]));
            float ng = (1.0f - ec) * __builtin_amdgcn_rcpf(1.0f + ec);
            float h = (1.0f - zg) * ng + zg * ho[r];
            ho[r] = h;
            h_s[1][wrow + r][wcol] = (f16)h;
        }
    }
    // steps 1..63: xin == h -> combined weights, register-resident (pinned)
    {
        f16x8 wd_r[4], wd_z[4], wd_xn[4], wd_hn[4];
        { int gr = j0 + nl;
          #pragma unroll
          for (int kt = 0; kt < 4; kt++) {
              wd_r[kt]  = *(const f16x8*)(dwc + gr * 128 + kt * 32 + quad * 8);
              wd_z[kt]  = *(const f16x8*)(dwc + (128 + gr) * 128 + kt * 32 + quad * 8);
              wd_xn[kt] = *(const f16x8*)(dwc + (256 + gr) * 128 + kt * 32 + quad * 8);
              wd_hn[kt] = *(const f16x8*)(dwc + (384 + gr) * 128 + kt * 32 + quad * 8);
              pin(wd_r[kt]); pin(wd_z[kt]); pin(wd_xn[kt]); pin(wd_hn[kt]);
          }
        }

#define DEC_STEP(BUF, OBUF)                                                          \
        do {                                                                         \
            __syncthreads();                                                         \
            f16x8 ah0 = *(const f16x8*)(&h_s[BUF][nl][c0]);                          \
            f16x8 ah1 = *(const f16x8*)(&h_s[BUF][nl][c1]);                          \
            f16x8 ah2 = *(const f16x8*)(&h_s[BUF][nl][c2]);                          \
            f16x8 ah3 = *(const f16x8*)(&h_s[BUF][nl][c3]);                          \
            f32x4 aR  = {db_r, db_r, db_r, db_r};                                    \
            f32x4 aZ  = {db_z, db_z, db_z, db_z};                                    \
            f32x4 aXN = {db_xn, db_xn, db_xn, db_xn};                                \
            f32x4 aHN = {db_hn, db_hn, db_hn, db_hn};                                \
            aR  = mfma16(ah0, wd_r[0], aR);   aR  = mfma16(ah1, wd_r[1], aR);        \
            aR  = mfma16(ah2, wd_r[2], aR);   aR  = mfma16(ah3, wd_r[3], aR);        \
            aZ  = mfma16(ah0, wd_z[0], aZ);   aZ  = mfma16(ah1, wd_z[1], aZ);        \
            aZ  = mfma16(ah2, wd_z[2], aZ);   aZ  = mfma16(ah3, wd_z[3], aZ);        \
            aXN = mfma16(ah0, wd_xn[0], aXN); aXN = mfma16(ah1, wd_xn[1], aXN);      \
            aXN = mfma16(ah2, wd_xn[2], aXN); aXN = mfma16(ah3, wd_xn[3], aXN);      \
            aHN = mfma16(ah0, wd_hn[0], aHN); aHN = mfma16(ah1, wd_hn[1], aHN);      \
            aHN = mfma16(ah2, wd_hn[2], aHN); aHN = mfma16(ah3, wd_hn[3], aHN);      \
            _Pragma("unroll")                                                        \
            for (int r = 0; r < 4; r++) {                                            \
                float ea = fexp2n(aR[r]), eb = fexp2n(aZ[r]);                        \
                float s1 = 1.0f + ea, s2 = 1.0f + eb;                                \
                float R = __builtin_amdgcn_rcpf(s1 * s2);                            \
                float rg = s2 * R, zg = s1 * R;                                      \
                float ec = fexp2n(2.0f * (aXN[r] + rg * aHN[r]));                    \
                float ng = (1.0f - ec) * __builtin_amdgcn_rcpf(1.0f + ec);           \
                float h = (1.0f - zg) * ng + zg * ho[r];                             \
                ho[r] = h;                                                           \
                h_s[OBUF][wrow + r][wcol] = (f16)h;                                  \
            }                                                                        \
        } while (0)

        DEC_STEP(1, 0);            // step 1
        for (int t = 2; t < 64; t += 2) {
            DEC_STEP(0, 1);
            DEC_STEP(1, 0);
        }
#undef DEC_STEP
    }

    // ================= heads =================
    #pragma unroll
    for (int r = 0; r < 4; r++)
        pn_s[wrow + r][128 + j0 + nl] = ho[r];
    for (int i = tid; i < 16 * 128; i += 512) {
        int rr = i >> 7, cc = i & 127;
        pn_s[rr][cc] = z_cnn[(size_t)(row0 + rr) * 128 + cc];
    }
    __syncthreads();

    const int rr = tid & 15, og = tid >> 4;   // og 0..31
    const float4* pr4 = (const float4*)(&pn_s[rr][0]);
    for (int o = og; o < 79; o += 32) {
        const float* wrow_p = (o < 78) ? (dis_w + o * 256) : value_w;
        float acc = (o < 78) ? dis_b[o] : value_b[0];
        const float4* wr4 = (const float4*)wrow_p;
        #pragma unroll 8
        for (int k = 0; k < 64; k++) {
            float4 a = wr4[k], b = pr4[k];
            acc += a.x * b.x + a.y * b.y + a.z * b.z + a.w * b.w;
        }
        if (o < 78) out[(size_t)(row0 + rr) * 78 + o] = acc;
        else        out[(size_t)8192 * 78 + row0 + rr] = acc;
    }
}

extern "C" void kernel_launch(void* const* d_in, const int* in_sizes, int n_in,
                              void* d_out, int out_size, void* d_ws, size_t ws_size,
                              hipStream_t stream)
{
    (void)in_sizes; (void)n_in; (void)out_size; (void)ws_size;
    const float* cnn  = (const float*)d_in[0];
    const float* lin  = (const float*)d_in[1];
    const float* c1w  = (const float*)d_in[2];
    const float* c1b  = (const float*)d_in[3];
    const float* c2w  = (const float*)d_in[4];
    const float* c2b  = (const float*)d_in[5];
    const float* fcw  = (const float*)d_in[6];
    const float* fcb  = (const float*)d_in[7];
    const float* eWih = (const float*)d_in[8];
    const float* eWhh = (const float*)d_in[9];
    const float* ebih = (const float*)d_in[10];
    const float* ebhh = (const float*)d_in[11];
    const float* dWih = (const float*)d_in[12];
    const float* dWhh = (const float*)d_in[13];
    const float* dbih = (const float*)d_in[14];
    const float* dbhh = (const float*)d_in[15];
    const float* disw = (const float*)d_in[16];
    const float* disb = (const float*)d_in[17];
    const float* vw   = (const float*)d_in[18];
    const float* vb   = (const float*)d_in[19];
    char* ws = (char*)d_ws;
    float* out = (float*)d_out;

    hipLaunchKernelGGL(k_prep, dim3(128), dim3(256), 0, stream,
                       eWih, eWhh, ebih, ebhh, dWih, dWhh, dbih, dbhh,
                       c1w, c2w, fcw, ws);
    hipLaunchKernelGGL(k_cnn, dim3(512), dim3(256), 0, stream,
                       cnn, c1b, c2b, fcb, ws);
    hipLaunchKernelGGL(k_gru, dim3(512), dim3(512), 0, stream,
                       lin, ws, disw, disb, vw, vb, out);
}

// Round 6
// 331.710 us; speedup vs baseline: 1.1956x; 1.0553x over previous
//
#include <hip/hip_runtime.h>

typedef _Float16 f16;
typedef _Float16 f16x8 __attribute__((ext_vector_type(8)));
typedef float f32x4 __attribute__((ext_vector_type(4)));

// ---- workspace layout (bytes) ----
#define WS_EWIH 4194304                // enc Wih f16 [384][32] (k>=29 zero)
#define WS_EWHH 4218880                // enc Whh f16 [384][128]
#define WS_DWC  4317184                // dec combined f16 [512][128]
#define WS_DWHH 4448256                // dec Whh f16 [384][128]
#define WS_BIAS 4546560                // f32[1024]
#define WS_W1F  4550656                // conv1 B-frags f16 [9][16][32]
#define WS_W2F  4559872                // conv2 B-frags f16 [2][32][32]
#define WS_FCWF 4563968                // fc weights f16 [128][128]

static __device__ __forceinline__ f32x4 mfma16(f16x8 a, f16x8 b, f32x4 c) {
    return __builtin_amdgcn_mfma_f32_16x16x32_f16(a, b, c, 0, 0, 0);
}
static __device__ __forceinline__ float fexp2n(float x) {   // 2^(-x*log2e)
    return __builtin_amdgcn_exp2f(x * -1.4426950408889634f);
}

// ---------------- prep: f32 -> f16 packs ----------------
__global__ void k_prep(const float* __restrict__ eWih, const float* __restrict__ eWhh,
                       const float* __restrict__ ebih, const float* __restrict__ ebhh,
                       const float* __restrict__ dWih, const float* __restrict__ dWhh,
                       const float* __restrict__ dbih, const float* __restrict__ dbhh,
                       const float* __restrict__ w1, const float* __restrict__ w2,
                       const float* __restrict__ fcw,
                       char* __restrict__ ws)
{
    f16* ewih = (f16*)(ws + WS_EWIH);
    f16* ewhh = (f16*)(ws + WS_EWHH);
    f16* dwc  = (f16*)(ws + WS_DWC);
    f16* dwhh = (f16*)(ws + WS_DWHH);
    float* bias = (float*)(ws + WS_BIAS);
    f16* w1f = (f16*)(ws + WS_W1F);
    f16* w2f = (f16*)(ws + WS_W2F);
    f16* fcwf = (f16*)(ws + WS_FCWF);
    const int total = 12288 + 49152 + 65536 + 49152 + 1024 + 4608 + 2048 + 16384;
    for (int i = blockIdx.x * 256 + threadIdx.x; i < total; i += gridDim.x * 256) {
        int j = i;
        if (j < 12288) { int g = j >> 5, k = j & 31;
            ewih[j] = (f16)((k < 29) ? eWih[g * 29 + k] : 0.0f); continue; }
        j -= 12288;
        if (j < 49152) { ewhh[j] = (f16)eWhh[j]; continue; }
        j -= 49152;
        if (j < 65536) { int row = j >> 7, k = j & 127; float v;
            if (row < 256)      v = dWih[row * 128 + k] + dWhh[row * 128 + k];
            else if (row < 384) v = dWih[row * 128 + k];
            else                v = dWhh[(row - 128) * 128 + k];
            dwc[j] = (f16)v; continue; }
        j -= 65536;
        if (j < 49152) { dwhh[j] = (f16)dWhh[j]; continue; }
        j -= 49152;
        if (j < 1024) {
            if (j < 256)        bias[j] = ebih[j] + ebhh[j];
            else if (j < 384)   bias[j] = ebih[j];
            else if (j < 512)   bias[j] = ebhh[j - 128];
            else if (j < 768)   bias[j] = dbih[j - 512] + dbhh[j - 512];
            else if (j < 896)   bias[j] = dbih[j - 512];
            else                bias[j] = dbhh[j - 640];
            continue; }
        j -= 1024;
        if (j < 4608) {   // w1f[kk][co][k]: w1 (16,27,3,3) OIHW; k>=27 -> 0
            int kk = j >> 9, rem = j & 511, co = rem >> 5, k = rem & 31;
            w1f[j] = (f16)((k < 27) ? w1[co * 243 + k * 9 + kk] : 0.0f); continue; }
        j -= 4608;
        if (j < 2048) {   // w2f[s][co][k]
            int s = j >> 10, rem = j & 1023, co = rem >> 5, k = rem & 31;
            int kk2 = 2 * s + (k >= 16), ci = k & 15;
            w2f[j] = (f16)w2[co * 64 + ci * 4 + kk2]; continue; }
        j -= 2048;
        fcwf[j] = (f16)fcw[j];
    }
}

// ---------------- fused CNN + GRU + heads: 512 threads, 16 rows/block ----------------
// CNN prologue writes z_cnn directly into pn_s cols 0..127 (no global round-trip,
// no separate kernel). a1f aliases the h_s region (h_s zero-init happens after).
__global__ __launch_bounds__(512, 4) void k_gru(
    const float* __restrict__ cin,
    const float* __restrict__ lin,
    const float* __restrict__ b1, const float* __restrict__ b2,
    const float* __restrict__ fcb,
    const char* __restrict__ ws,
    const float* __restrict__ dis_w, const float* __restrict__ dis_b,
    const float* __restrict__ value_w, const float* __restrict__ value_b,
    float* __restrict__ out)
{
    __shared__ __align__(16) char smem[32000];
    f16 (*h_s)[16][136]  = (f16(*)[16][136])(smem);            // 8704 B
    f16 (*x_s)[16][32]   = (f16(*)[16][32])(smem + 8704);      // 2048 B
    float (*pn_s)[264]   = (float(*)[264])(smem + 10752);      // 16896 B
    f16 (*a1f)[9][24]    = (f16(*)[9][24])(smem);              // 6912 B, aliases h_s (CNN phase only)
    f16 (*vf)[136]       = (f16(*)[136])(smem + 27648);        // 4352 B

    const int tid = threadIdx.x;
    const int wv = tid >> 6;
    const int lane = tid & 63;
    const int nl = lane & 15;
    const int quad = lane >> 4;
    const int j0 = wv * 16;
    const int row0 = blockIdx.x * 16;

    const f16* ewih = (const f16*)(ws + WS_EWIH);
    const f16* ewhh = (const f16*)(ws + WS_EWHH);
    const f16* dwc  = (const f16*)(ws + WS_DWC);
    const f16* dwhh = (const f16*)(ws + WS_DWHH);
    const float* bias = (const float*)(ws + WS_BIAS);
    const f16* w1f = (const f16*)(ws + WS_W1F);
    const f16* w2f = (const f16*)(ws + WS_W2F);
    const f16* fcwf = (const f16*)(ws + WS_FCWF);

    // ================= CNN prologue (16 images = this block's rows) =================
    {
        // conv1: 9 output positions over 8 waves; A direct from global (pad chans hit zero B rows)
        const float* imgp = cin + (size_t)(row0 + nl) * 1728 + quad * 8;
        float b1v = b1[nl];
        for (int p = wv; p < 9; p += 8) {
            int oy = p / 3, ox = p % 3;
            f32x4 acc = {b1v, b1v, b1v, b1v};
            #pragma unroll
            for (int kk = 0; kk < 9; kk++) {
                f16x8 bw = *(const f16x8*)(w1f + (kk * 16 + nl) * 32 + quad * 8);
                int pix = (2 * oy + kk / 3) * 8 + (2 * ox + kk % 3);
                const float* s = imgp + pix * 27;
                f16x8 a;
                #pragma unroll
                for (int jj = 0; jj < 8; jj++) a[jj] = (f16)s[jj];
                acc = mfma16(a, bw, acc);
            }
            #pragma unroll
            for (int r = 0; r < 4; r++)
                a1f[quad * 4 + r][p][nl] = (f16)fmaxf(acc[r], 0.0f);
        }
        __syncthreads();
        // conv2: 4 positions x 2 nt = 8 units -> one per wave
        {
            int pos = wv >> 1, nt = wv & 1;
            int y = pos >> 1, x = pos & 1;
            float bv = b2[nt * 16 + nl];
            f32x4 acc = {bv, bv, bv, bv};
            #pragma unroll
            for (int s = 0; s < 2; s++) {
                int kk2 = 2 * s + (quad >> 1);
                int pos1 = (y + (kk2 >> 1)) * 3 + (x + (kk2 & 1));
                f16x8 a = *(const f16x8*)(&a1f[nl][pos1][(quad & 1) * 8]);
                f16x8 b = *(const f16x8*)(w2f + ((size_t)s * 32 + nt * 16 + nl) * 32 + quad * 8);
                acc = mfma16(a, b, acc);
            }
            #pragma unroll
            for (int r = 0; r < 4; r++)
                vf[quad * 4 + r][(nt * 16 + nl) * 4 + (y * 2 + x)] = (f16)fmaxf(acc[r], 0.0f);
        }
        __syncthreads();
        // fc 128->128: wave wv -> outputs wv*16..wv*16+15, straight into pn_s[:, 0..127]
        {
            int o = wv * 16 + nl;
            float bv = fcb[o];
            f32x4 acc = {bv, bv, bv, bv};
            #pragma unroll
            for (int kt = 0; kt < 4; kt++) {
                f16x8 a = *(const f16x8*)(&vf[nl][kt * 32 + quad * 8]);
                f16x8 b = *(const f16x8*)(fcwf + o * 128 + kt * 32 + quad * 8);
                acc = mfma16(a, b, acc);
            }
            #pragma unroll
            for (int r = 0; r < 4; r++)
                pn_s[quad * 4 + r][o] = fmaxf(acc[r], 0.0f);
        }
        __syncthreads();   // a1f dead; safe to zero h_s below
    }

    for (int i = tid; i < 2 * 16 * 136; i += 512) ((f16*)h_s)[i] = (f16)0.0f;

    const int rsw = (nl & 8) ? 16 : 0;    // read-side swizzle (row = nl)
    const int wrow = quad * 4;            // write rows wrow..wrow+3
    const int wsw = (quad >= 2) ? 16 : 0; // write-side swizzle (rows 8-15)
    const int wcol = (j0 + nl + wsw) & 127;
    const int c0 = (quad * 8 + rsw) & 127;
    const int c1 = (32 + quad * 8 + rsw) & 127;
    const int c2 = (64 + quad * 8 + rsw) & 127;
    const int c3 = (96 + quad * 8 + rsw) & 127;

    float ho[4];
    #pragma unroll
    for (int r = 0; r < 4; r++) ho[r] = 0.0f;

    const int xr = tid >> 5, xc = tid & 31;   // x staging: 16 rows x 32 cols
    const bool xok = (xc < 29);
    const size_t lin_base = (size_t)(row0 + xr) * 1856 + xc;

    // ================= encoder =================
    {
        float eb_r, eb_z, eb_xn, eb_hn;
        { int c = j0 + nl;
          eb_r = bias[c]; eb_z = bias[128 + c]; eb_xn = bias[256 + c]; eb_hn = bias[384 + c]; }
        f16x8 we_r[4], we_z[4], we_hn[4], we_xr, we_xz, we_xn;
        { int gr = j0 + nl;
          #pragma unroll
          for (int kt = 0; kt < 4; kt++) {
              we_r[kt]  = *(const f16x8*)(ewhh + gr * 128 + kt * 32 + quad * 8);
              we_z[kt]  = *(const f16x8*)(ewhh + (128 + gr) * 128 + kt * 32 + quad * 8);
              we_hn[kt] = *(const f16x8*)(ewhh + (256 + gr) * 128 + kt * 32 + quad * 8);
          }
          we_xr = *(const f16x8*)(ewih + gr * 32 + quad * 8);
          we_xz = *(const f16x8*)(ewih + (128 + gr) * 32 + quad * 8);
          we_xn = *(const f16x8*)(ewih + (256 + gr) * 32 + quad * 8);
        }

        float xv = xok ? lin[lin_base] : 0.0f;

#define ENC_STEP(BUF, OBUF, TN)                                                      \
        do {                                                                         \
            x_s[BUF][xr][xc] = (f16)xv;                                              \
            __syncthreads();                                                         \
            f16x8 ax = *(const f16x8*)(&x_s[BUF][nl][quad * 8]);                     \
            f16x8 ah0 = *(const f16x8*)(&h_s[BUF][nl][c0]);                          \
            f16x8 ah1 = *(const f16x8*)(&h_s[BUF][nl][c1]);                          \
            f16x8 ah2 = *(const f16x8*)(&h_s[BUF][nl][c2]);                          \
            f16x8 ah3 = *(const f16x8*)(&h_s[BUF][nl][c3]);                          \
            if ((TN) < 64) xv = xok ? lin[lin_base + (TN) * 29] : 0.0f;              \
            f32x4 aR  = {eb_r, eb_r, eb_r, eb_r};                                    \
            f32x4 aZ  = {eb_z, eb_z, eb_z, eb_z};                                    \
            f32x4 aXN = {eb_xn, eb_xn, eb_xn, eb_xn};                                \
            f32x4 aHN = {eb_hn, eb_hn, eb_hn, eb_hn};                                \
            aR  = mfma16(ax, we_xr, aR);                                             \
            aZ  = mfma16(ax, we_xz, aZ);                                             \
            aXN = mfma16(ax, we_xn, aXN);                                            \
            aR  = mfma16(ah0, we_r[0], aR);  aR  = mfma16(ah1, we_r[1], aR);         \
            aR  = mfma16(ah2, we_r[2], aR);  aR  = mfma16(ah3, we_r[3], aR);         \
            aZ  = mfma16(ah0, we_z[0], aZ);  aZ  = mfma16(ah1, we_z[1], aZ);         \
            aZ  = mfma16(ah2, we_z[2], aZ);  aZ  = mfma16(ah3, we_z[3], aZ);         \
            aHN = mfma16(ah0, we_hn[0], aHN); aHN = mfma16(ah1, we_hn[1], aHN);      \
            aHN = mfma16(ah2, we_hn[2], aHN); aHN = mfma16(ah3, we_hn[3], aHN);      \
            _Pragma("unroll")                                                        \
            for (int r = 0; r < 4; r++) {                                            \
                float ea = fexp2n(aR[r]), eb = fexp2n(aZ[r]);                        \
                float s1 = 1.0f + ea, s2 = 1.0f + eb;                                \
                float R = __builtin_amdgcn_rcpf(s1 * s2);                            \
                float rg = s2 * R, zg = s1 * R;                                      \
                float ec = fexp2n(2.0f * (aXN[r] + rg * aHN[r]));                    \
                float ng = (1.0f - ec) * __builtin_amdgcn_rcpf(1.0f + ec);           \
                float h = ng + zg * (ho[r] - ng);                                    \
                ho[r] = h;                                                           \
                h_s[OBUF][wrow + r][wcol] = (f16)h;                                  \
            }                                                                        \
        } while (0)

        for (int t = 0; t < 64; t += 2) {
            ENC_STEP(0, 1, t + 1);
            ENC_STEP(1, 0, t + 2);
        }
#undef ENC_STEP
    }

    // ================= decoder =================
    float db_r, db_z, db_xn, db_hn;
    { int c = j0 + nl;
      db_r = bias[512 + c]; db_z = bias[640 + c]; db_xn = bias[768 + c]; db_hn = bias[896 + c]; }

    // step 0: xin = 0 -> gx = bih; Whh-only frags streamed once (reads h_s[0], writes h_s[1])
    {
        __syncthreads();
        f16x8 ah0 = *(const f16x8*)(&h_s[0][nl][c0]);
        f16x8 ah1 = *(const f16x8*)(&h_s[0][nl][c1]);
        f16x8 ah2 = *(const f16x8*)(&h_s[0][nl][c2]);
        f16x8 ah3 = *(const f16x8*)(&h_s[0][nl][c3]);
        int gr = j0 + nl;
        f32x4 aR  = {db_r, db_r, db_r, db_r};
        f32x4 aZ  = {db_z, db_z, db_z, db_z};
        f32x4 aHN = {db_hn, db_hn, db_hn, db_hn};
        #pragma unroll
        for (int kt = 0; kt < 4; kt++) {
            f16x8 b0 = *(const f16x8*)(dwhh + gr * 128 + kt * 32 + quad * 8);
            f16x8 b1 = *(const f16x8*)(dwhh + (128 + gr) * 128 + kt * 32 + quad * 8);
            f16x8 b2 = *(const f16x8*)(dwhh + (256 + gr) * 128 + kt * 32 + quad * 8);
            f16x8 a = (kt == 0) ? ah0 : (kt == 1) ? ah1 : (kt == 2) ? ah2 : ah3;
            aR  = mfma16(a, b0, aR);
            aZ  = mfma16(a, b1, aZ);
            aHN = mfma16(a, b2, aHN);
        }
        #pragma unroll
        for (int r = 0; r < 4; r++) {
            float ea = fexp2n(aR[r]), eb = fexp2n(aZ[r]);
            float s1 = 1.0f + ea, s2 = 1.0f + eb;
            float R = __builtin_amdgcn_rcpf(s1 * s2);
            float rg = s2 * R, zg = s1 * R;
            float ec = fexp2n(2.0f * (db_xn + rg * aHN[r]));
            float ng = (1.0f - ec) * __builtin_amdgcn_rcpf(1.0f + ec);
            float h = ng + zg * (ho[r] - ng);
            ho[r] = h;
            h_s[1][wrow + r][wcol] = (f16)h;
        }
    }
    // steps 1..63: xin == h -> combined weights
    {
        f16x8 wd_r[4], wd_z[4], wd_xn[4], wd_hn[4];
        { int gr = j0 + nl;
          #pragma unroll
          for (int kt = 0; kt < 4; kt++) {
              wd_r[kt]  = *(const f16x8*)(dwc + gr * 128 + kt * 32 + quad * 8);
              wd_z[kt]  = *(const f16x8*)(dwc + (128 + gr) * 128 + kt * 32 + quad * 8);
              wd_xn[kt] = *(const f16x8*)(dwc + (256 + gr) * 128 + kt * 32 + quad * 8);
              wd_hn[kt] = *(const f16x8*)(dwc + (384 + gr) * 128 + kt * 32 + quad * 8);
          }
        }

#define DEC_STEP(BUF, OBUF)                                                          \
        do {                                                                         \
            __syncthreads();                                                         \
            f16x8 ah0 = *(const f16x8*)(&h_s[BUF][nl][c0]);                          \
            f16x8 ah1 = *(const f16x8*)(&h_s[BUF][nl][c1]);                          \
            f16x8 ah2 = *(const f16x8*)(&h_s[BUF][nl][c2]);                          \
            f16x8 ah3 = *(const f16x8*)(&h_s[BUF][nl][c3]);                          \
            f32x4 aR  = {db_r, db_r, db_r, db_r};                                    \
            f32x4 aZ  = {db_z, db_z, db_z, db_z};                                    \
            f32x4 aXN = {db_xn, db_xn, db_xn, db_xn};                                \
            f32x4 aHN = {db_hn, db_hn, db_hn, db_hn};                                \
            aR  = mfma16(ah0, wd_r[0], aR);   aR  = mfma16(ah1, wd_r[1], aR);        \
            aR  = mfma16(ah2, wd_r[2], aR);   aR  = mfma16(ah3, wd_r[3], aR);        \
            aZ  = mfma16(ah0, wd_z[0], aZ);   aZ  = mfma16(ah1, wd_z[1], aZ);        \
            aZ  = mfma16(ah2, wd_z[2], aZ);   aZ  = mfma16(ah3, wd_z[3], aZ);        \
            aXN = mfma16(ah0, wd_xn[0], aXN); aXN = mfma16(ah1, wd_xn[1], aXN);      \
            aXN = mfma16(ah2, wd_xn[2], aXN); aXN = mfma16(ah3, wd_xn[3], aXN);      \
            aHN = mfma16(ah0, wd_hn[0], aHN); aHN = mfma16(ah1, wd_hn[1], aHN);      \
            aHN = mfma16(ah2, wd_hn[2], aHN); aHN = mfma16(ah3, wd_hn[3], aHN);      \
            _Pragma("unroll")                                                        \
            for (int r = 0; r < 4; r++) {                                            \
                float ea = fexp2n(aR[r]), eb = fexp2n(aZ[r]);                        \
                float s1 = 1.0f + ea, s2 = 1.0f + eb;                                \
                float R = __builtin_amdgcn_rcpf(s1 * s2);                            \
                float rg = s2 * R, zg = s1 * R;                                      \
                float ec = fexp2n(2.0f * (aXN[r] + rg * aHN[r]));                    \
                float ng = (1.0f - ec) * __builtin_amdgcn_rcpf(1.0f + ec);           \
                float h = ng + zg * (ho[r] - ng);                                    \
                ho[r] = h;                                                           \
                h_s[OBUF][wrow + r][wcol] = (f16)h;                                  \
            }                                                                        \
        } while (0)

        DEC_STEP(1, 0);            // step 1
        for (int t = 2; t < 64; t += 2) {
            DEC_STEP(0, 1);
            DEC_STEP(1, 0);
        }
#undef DEC_STEP
    }

    // ================= heads (pn_s cols 0..127 already hold z_cnn) =================
    #pragma unroll
    for (int r = 0; r < 4; r++)
        pn_s[wrow + r][128 + j0 + nl] = ho[r];
    __syncthreads();

    const int rr = tid & 15, og = tid >> 4;   // og 0..31
    const float4* pr4 = (const float4*)(&pn_s[rr][0]);
    for (int o = og; o < 79; o += 32) {
        const float* wrow_p = (o < 78) ? (dis_w + o * 256) : value_w;
        float acc = (o < 78) ? dis_b[o] : value_b[0];
        const float4* wr4 = (const float4*)wrow_p;
        #pragma unroll 8
        for (int k = 0; k < 64; k++) {
            float4 a = wr4[k], b = pr4[k];
            acc += a.x * b.x + a.y * b.y + a.z * b.z + a.w * b.w;
        }
        if (o < 78) out[(size_t)(row0 + rr) * 78 + o] = acc;
        else        out[(size_t)8192 * 78 + row0 + rr] = acc;
    }
}

extern "C" void kernel_launch(void* const* d_in, const int* in_sizes, int n_in,
                              void* d_out, int out_size, void* d_ws, size_t ws_size,
                              hipStream_t stream)
{
    (void)in_sizes; (void)n_in; (void)out_size; (void)ws_size;
    const float* cnn  = (const float*)d_in[0];
    const float* lin  = (const float*)d_in[1];
    const float* c1w  = (const float*)d_in[2];
    const float* c1b  = (const float*)d_in[3];
    const float* c2w  = (const float*)d_in[4];
    const float* c2b  = (const float*)d_in[5];
    const float* fcw  = (const float*)d_in[6];
    const float* fcb  = (const float*)d_in[7];
    const float* eWih = (const float*)d_in[8];
    const float* eWhh = (const float*)d_in[9];
    const float* ebih = (const float*)d_in[10];
    const float* ebhh = (const float*)d_in[11];
    const float* dWih = (const float*)d_in[12];
    const float* dWhh = (const float*)d_in[13];
    const float* dbih = (const float*)d_in[14];
    const float* dbhh = (const float*)d_in[15];
    const float* disw = (const float*)d_in[16];
    const float* disb = (const float*)d_in[17];
    const float* vw   = (const float*)d_in[18];
    const float* vb   = (const float*)d_in[19];
    char* ws = (char*)d_ws;
    float* out = (float*)d_out;

    hipLaunchKernelGGL(k_prep, dim3(128), dim3(256), 0, stream,
                       eWih, eWhh, ebih, ebhh, dWih, dWhh, dbih, dbhh,
                       c1w, c2w, fcw, ws);
    hipLaunchKernelGGL(k_gru, dim3(512), dim3(512), 0, stream,
                       cnn, lin, c1b, c2b, fcb, ws, disw, disb, vw, vb, out);
}